// Round 1
// baseline (206.652 us; speedup 1.0000x reference)
//
#include <hip/hip_runtime.h>
#include <stdint.h>

// Problem constants (fixed by the reference setup):
//   logits (2,4,128,128,128) fp32, target one-hot same shape.
#define NVOX (1u << 21)            // 128^3 voxels per batch (exactly 2^21)
#define NB   2                     // batches
#define KSEL 419430u               // int(0.2 * 2^21)
#define TPB  256
#define VPB  2048                  // voxels per block (halved: 8 blocks/CU now)
#define BPB  ((int)(NVOX / VPB))   // 1024 blocks per batch
#define NBLK (NB * BPB)            // 2048 blocks = exactly 8/CU on 256 CUs
#define NCOPY 64                   // accumulator spreading (dice + topk partials)
#define NHC  16                    // histogram spread copies
#define NBINS 4096                 // 12-bit bins: sign(0)+exp(8)+mantissa(4)
#define SH   19                    // bin = bits >> 19 (CE >= 0 so sign bit = 0)
#define SVPB 4096                  // voxels per block in k_sum
#define SBPB ((int)(NVOX / SVPB))  // 512
#define SBLK (NB * SBPB)           // 1024

__device__ __forceinline__ float wred64(float v) {
#pragma unroll
  for (int o = 32; o > 0; o >>= 1) v += __shfl_down(v, o, 64);
  return v;
}

// Pass 1: CE per voxel -> (a) fp32 CE store (coalesced float4), (b) 32-bit
// count-only LDS histogram (16 KB -> 8 blocks/CU), (c) dice partial sums.
__global__ __launch_bounds__(TPB, 8) void k1_fused(
    const float* __restrict__ logits, const float* __restrict__ target,
    float* __restrict__ ce, uint32_t* __restrict__ hcnt,
    float* __restrict__ dice_acc /* [NCOPY][NB][12]: sp[4], num[4], cnt[4] */)
{
  __shared__ uint32_t hbin[NBINS];   // 16 KB
  const int tid = threadIdx.x;
  for (int i = tid; i < NBINS; i += TPB) hbin[i] = 0u;
  __syncthreads();

  const int blk = blockIdx.x;
  const int b = blk / BPB;
  const size_t v0 = (size_t)(blk % BPB) * VPB;
  const float* lg = logits + (size_t)b * 4 * NVOX + v0;
  const float* tg = target + (size_t)b * 4 * NVOX + v0;
  float* cd = ce + (size_t)b * NVOX + v0;

  float sp[4] = {0.f,0.f,0.f,0.f}, nm[4] = {0.f,0.f,0.f,0.f}, ct[4] = {0.f,0.f,0.f,0.f};

#pragma unroll
  for (int it = 0; it < VPB / (TPB * 4); ++it) {   // exactly 2 iterations
    const int i = it * (TPB * 4) + tid * 4;
    float4 L[4], T[4];
#pragma unroll
    for (int c = 0; c < 4; ++c) {
      L[c] = *(const float4*)(lg + (size_t)c * NVOX + i);
      T[c] = *(const float4*)(tg + (size_t)c * NVOX + i);
    }
    float4 cv;
#pragma unroll
    for (int j = 0; j < 4; ++j) {
      float l[4], t[4];
#pragma unroll
      for (int c = 0; c < 4; ++c) {
        l[c] = ((const float*)&L[c])[j];
        t[c] = ((const float*)&T[c])[j];
      }
      float m = fmaxf(fmaxf(l[0], l[1]), fmaxf(l[2], l[3]));
      float e[4]; float s = 0.f;
#pragma unroll
      for (int c = 0; c < 4; ++c) { e[c] = __expf(l[c] - m); s += e[c]; }
      float inv = 1.f / s;
      float lse = __logf(s);                       // s >= 1 -> lse >= 0
      float ly = l[0]*t[0] + l[1]*t[1] + l[2]*t[2] + l[3]*t[3]; // exact: t one-hot
      float cev = (m - ly) + lse;                  // >= 0
      ((float*)&cv)[j] = cev;
      uint32_t idx = __float_as_uint(cev) >> SH;   // monotone in cev
      if (idx > NBINS - 1) idx = NBINS - 1;
      atomicAdd(&hbin[idx], 1u);                   // 4B LDS RMW (was 8B)
#pragma unroll
      for (int c = 0; c < 4; ++c) {
        float p = e[c] * inv;
        sp[c] += p;
        nm[c] += p * t[c];
        ct[c] += t[c];
      }
    }
    *(float4*)(cd + i) = cv;                       // coalesced CE store
  }

  // dice: wave-reduce then one atomic per component per wave into a spread copy
#pragma unroll
  for (int c = 0; c < 4; ++c) { sp[c] = wred64(sp[c]); nm[c] = wred64(nm[c]); ct[c] = wred64(ct[c]); }
  if ((tid & 63) == 0) {
    float* dst = dice_acc + ((size_t)(blk & (NCOPY - 1)) * NB + b) * 12;
#pragma unroll
    for (int c = 0; c < 4; ++c) {
      atomicAdd(dst + c,     sp[c]);
      atomicAdd(dst + 4 + c, nm[c]);
      atomicAdd(dst + 8 + c, ct[c]);
    }
  }
  __syncthreads();
  // Flush LDS count histogram into this block's spread copy.
  const size_t hoff = ((size_t)b * NHC + (size_t)(blk & (NHC - 1))) * NBINS;
  uint32_t* cdst = hcnt + hoff;
  for (int i = tid; i < NBINS; i += TPB) {
    uint32_t v = hbin[i];
    if (v) atomicAdd(&cdst[i], v);
  }
}

// Collapse the NHC count copies and find the tie bin per batch.
// pick[b*4] = {bkt, rem, cnt_t, unused}
__global__ __launch_bounds__(256) void k_pick(
    const uint32_t* __restrict__ hcnt, uint32_t* __restrict__ pick)
{
  __shared__ uint32_t shc[NBINS];   // 16 KB
  __shared__ uint32_t chunk[256];
  const int b = blockIdx.x;
  const int tid = threadIdx.x;
  uint32_t acc[16];
#pragma unroll
  for (int q = 0; q < 16; ++q) acc[q] = 0u;
  for (int copy = 0; copy < NHC; ++copy) {
    const uint32_t* src = hcnt + ((size_t)b * NHC + copy) * NBINS + tid * 16;
#pragma unroll
    for (int q = 0; q < 4; ++q) {
      uint4 v = *(const uint4*)(src + q * 4);
      acc[q*4+0] += v.x; acc[q*4+1] += v.y; acc[q*4+2] += v.z; acc[q*4+3] += v.w;
    }
  }
  uint32_t s = 0;
#pragma unroll
  for (int q = 0; q < 16; ++q) { shc[tid * 16 + q] = acc[q]; s += acc[q]; }
  chunk[tid] = s;
  __syncthreads();
  if (tid == 0) {
    uint32_t k = KSEL, cum = 0;
    int ci = 255;
    for (; ci > 0; --ci) {
      uint32_t c = chunk[ci];
      if (cum + c >= k) break;
      cum += c;
    }
    int bkt = ci * 16;
    for (int j = 15; j >= 0; --j) {
      uint32_t c = shc[ci * 16 + j];
      if (cum + c >= k) { bkt = ci * 16 + j; break; }
      cum += c;
    }
    pick[b * 4 + 0] = (uint32_t)bkt;
    pick[b * 4 + 1] = k - cum;        // 1 <= rem <= cnt_t
    pick[b * 4 + 2] = shc[bkt];       // cnt_t
  }
}

// Re-read CE (L3-resident) and compute exact fp32 sums: above-bin and tie-bin.
__global__ __launch_bounds__(256) void k_sum(
    const float* __restrict__ ce, const uint32_t* __restrict__ pick,
    float* __restrict__ tacc /* [NCOPY][NB][2]: above, tie */)
{
  const int blk = blockIdx.x;
  const int b = blk / SBPB;
  const uint32_t bkt = pick[b * 4];
  const float4* src = (const float4*)(ce + (size_t)b * NVOX + (size_t)(blk % SBPB) * SVPB);
  float4 v[4];
#pragma unroll
  for (int q = 0; q < 4; ++q) v[q] = src[threadIdx.x + q * 256];  // 4 loads in flight
  float ab = 0.f, ti = 0.f;
#pragma unroll
  for (int q = 0; q < 4; ++q) {
#pragma unroll
    for (int j = 0; j < 4; ++j) {
      float x = ((const float*)&v[q])[j];
      uint32_t idx = __float_as_uint(x) >> SH;
      if (idx > NBINS - 1) idx = NBINS - 1;      // must match k1's clamp
      ab += (idx > bkt)  ? x : 0.f;
      ti += (idx == bkt) ? x : 0.f;
    }
  }
  ab = wred64(ab); ti = wred64(ti);
  if ((threadIdx.x & 63) == 0) {
    float* d = tacc + ((size_t)(blk & (NCOPY - 1)) * NB + b) * 2;
    atomicAdd(d,     ab);
    atomicAdd(d + 1, ti);
  }
}

// Final: combine topk partials (uniform-density tie estimate) + dice.
__global__ __launch_bounds__(256) void k_final(
    const uint32_t* __restrict__ pick, const float* __restrict__ tacc,
    const float* __restrict__ dice_acc, float* __restrict__ out)
{
  __shared__ float comp[24];
  __shared__ float tt[4];
  const int tid = threadIdx.x;
  if (tid < 24) {
    float a = 0.f;
    for (int r = 0; r < NCOPY; ++r) a += dice_acc[(size_t)r * 24 + tid];
    comp[tid] = a;
  } else if (tid >= 32 && tid < 36) {
    const int j = tid - 32;
    float a = 0.f;
    for (int r = 0; r < NCOPY; ++r) a += tacc[(size_t)r * 4 + j];
    tt[j] = a;
  }
  __syncthreads();
  if (tid == 0) {
    float ts2 = 0.f;
#pragma unroll
    for (int b = 0; b < NB; ++b) {
      uint32_t bkt = pick[b * 4], rem = pick[b * 4 + 1], cnt = pick[b * 4 + 2];
      float above = tt[b * 2], ties = tt[b * 2 + 1];
      float lo = __uint_as_float(bkt << SH);
      float hi = __uint_as_float((bkt + 1) << SH);
      float width = hi - lo;
      float avg = ties / (float)cnt;
      float frac = (float)rem / (float)cnt;
      float est = avg + (1.f - frac) * 0.5f * width;   // uniform-density model
      ts2 += above + (float)rem * est;
    }
    float dl = 0.f;
#pragma unroll
    for (int b = 0; b < 2; ++b)
#pragma unroll
      for (int c = 1; c < 4; ++c) {
        float sp = comp[b * 12 + c];
        float nm = comp[b * 12 + 4 + c];
        float ct = comp[b * 12 + 8 + c];
        dl += 1.f - (2.f * nm) / (sp + ct + 1e-6f);
      }
    float topk = 0.5f * ts2 / (float)KSEL;
    out[0] = topk + 0.5f * (dl / 6.f);
  }
}

extern "C" void kernel_launch(void* const* d_in, const int* in_sizes, int n_in,
                              void* d_out, int out_size, void* d_ws, size_t ws_size,
                              hipStream_t stream) {
  (void)in_sizes; (void)n_in; (void)out_size; (void)ws_size;
  const float* logits = (const float*)d_in[0];
  const float* target = (const float*)d_in[1];
  float* out = (float*)d_out;

  // Workspace layout:
  //   [hcnt 512KB][dice 6KB][tacc 1KB]   <- memset to 0 (accumulators)
  //   [pick 32B]                         <- fully written by k_pick
  //   [ce 16MB, 16B-aligned]             <- fully written by k1_fused
  char* ws = (char*)d_ws;
  uint32_t* hcnt = (uint32_t*)ws;                                    // NB*NHC*NBINS u32
  float*    dice_acc = (float*)(ws + (size_t)NB * NHC * NBINS * 4);  // NCOPY*NB*12
  float*    tacc = dice_acc + (size_t)NCOPY * NB * 12;               // NCOPY*NB*2
  uint32_t* pick = (uint32_t*)(tacc + (size_t)NCOPY * NB * 2);       // NB*4
  float*    ce = (float*)((char*)pick + 32);                         // NB*NVOX f32
  const size_t ZERO_BYTES = (size_t)((char*)pick - ws);

  // ws is re-poisoned to 0xAA before every launch: zero the accumulators.
  hipMemsetAsync(ws, 0, ZERO_BYTES, stream);

  k1_fused<<<NBLK, TPB, 0, stream>>>(logits, target, ce, hcnt, dice_acc);
  k_pick<<<NB, 256, 0, stream>>>(hcnt, pick);
  k_sum<<<SBLK, 256, 0, stream>>>(ce, pick, tacc);
  k_final<<<1, 256, 0, stream>>>(pick, tacc, dice_acc, out);
}

// Round 2
// 192.527 us; speedup vs baseline: 1.0734x; 1.0734x over previous
//
#include <hip/hip_runtime.h>
#include <stdint.h>

// Problem constants (fixed by the reference setup):
//   logits (2,4,128,128,128) fp32, target one-hot same shape.
#define NVOX (1u << 21)            // 128^3 voxels per batch (exactly 2^21)
#define NB   2                     // batches
#define KSEL 419430u               // int(0.2 * 2^21)
#define TPB  256
#define VPB  2048                  // voxels per block
#define BPB  ((int)(NVOX / VPB))   // 1024 blocks per batch
#define NBLK (NB * BPB)            // 2048 blocks
#define NCOPY 64                   // accumulator spreading (dice + topk partials)
#define NHC  16                    // histogram spread copies
#define NBINS 4096                 // 12-bit bins: sign(0)+exp(8)+mantissa(4)
#define SH   19                    // bin = bits >> 19 (CE >= 0 so sign bit = 0)
#define SVPB 4096                  // voxels per block in k_sum
#define SBPB ((int)(NVOX / SVPB))  // 512
#define SBLK (NB * SBPB)           // 1024

__device__ __forceinline__ float wred64(float v) {
#pragma unroll
  for (int o = 32; o > 0; o >>= 1) v += __shfl_down(v, o, 64);
  return v;
}

// Pass 1: CE per voxel -> (a) fp32 CE store (coalesced float4), (b) 32-bit
// count-only LDS histogram (16 KB), (c) dice partial sums.
// __launch_bounds__(256,6): VGPR cap ~85 keeps the 8xfloat4 load cluster
// (32 payload VGPRs) fully in flight -- min=8 (cap 64) made the allocator
// drop to 32 VGPRs and serialize the loads (measured: VALUBusy 17->15%).
__global__ __launch_bounds__(TPB, 6) void k1_fused(
    const float* __restrict__ logits, const float* __restrict__ target,
    float* __restrict__ ce, uint32_t* __restrict__ hcnt,
    float* __restrict__ dice_acc /* [NCOPY][NB][12]: sp[4], num[4], cnt[4] */)
{
  __shared__ uint32_t hbin[NBINS];   // 16 KB
  const int tid = threadIdx.x;
  for (int i = tid; i < NBINS; i += TPB) hbin[i] = 0u;
  __syncthreads();

  const int blk = blockIdx.x;
  const int b = blk / BPB;
  const size_t v0 = (size_t)(blk % BPB) * VPB;
  const float* lg = logits + (size_t)b * 4 * NVOX + v0;
  const float* tg = target + (size_t)b * 4 * NVOX + v0;
  float* cd = ce + (size_t)b * NVOX + v0;

  float sp[4] = {0.f,0.f,0.f,0.f}, nm[4] = {0.f,0.f,0.f,0.f}, ct[4] = {0.f,0.f,0.f,0.f};

#pragma unroll
  for (int it = 0; it < VPB / (TPB * 4); ++it) {   // exactly 2 iterations
    const int i = it * (TPB * 4) + tid * 4;
    float4 L[4], T[4];
#pragma unroll
    for (int c = 0; c < 4; ++c) {
      L[c] = *(const float4*)(lg + (size_t)c * NVOX + i);
      T[c] = *(const float4*)(tg + (size_t)c * NVOX + i);
    }
    float4 cv;
#pragma unroll
    for (int j = 0; j < 4; ++j) {
      float l[4], t[4];
#pragma unroll
      for (int c = 0; c < 4; ++c) {
        l[c] = ((const float*)&L[c])[j];
        t[c] = ((const float*)&T[c])[j];
      }
      float m = fmaxf(fmaxf(l[0], l[1]), fmaxf(l[2], l[3]));
      float e[4]; float s = 0.f;
#pragma unroll
      for (int c = 0; c < 4; ++c) { e[c] = __expf(l[c] - m); s += e[c]; }
      float inv = 1.f / s;
      float lse = __logf(s);                       // s >= 1 -> lse >= 0
      float ly = l[0]*t[0] + l[1]*t[1] + l[2]*t[2] + l[3]*t[3]; // exact: t one-hot
      float cev = (m - ly) + lse;                  // >= 0
      ((float*)&cv)[j] = cev;
      uint32_t idx = __float_as_uint(cev) >> SH;   // monotone in cev
      if (idx > NBINS - 1) idx = NBINS - 1;
      atomicAdd(&hbin[idx], 1u);                   // 4B LDS RMW
#pragma unroll
      for (int c = 0; c < 4; ++c) {
        float p = e[c] * inv;
        sp[c] += p;
        nm[c] += p * t[c];
        ct[c] += t[c];
      }
    }
    *(float4*)(cd + i) = cv;                       // coalesced CE store
  }

  // dice: wave-reduce then one atomic per component per wave into a spread copy
#pragma unroll
  for (int c = 0; c < 4; ++c) { sp[c] = wred64(sp[c]); nm[c] = wred64(nm[c]); ct[c] = wred64(ct[c]); }
  if ((tid & 63) == 0) {
    float* dst = dice_acc + ((size_t)(blk & (NCOPY - 1)) * NB + b) * 12;
#pragma unroll
    for (int c = 0; c < 4; ++c) {
      atomicAdd(dst + c,     sp[c]);
      atomicAdd(dst + 4 + c, nm[c]);
      atomicAdd(dst + 8 + c, ct[c]);
    }
  }
  __syncthreads();
  // Flush LDS count histogram into this block's spread copy.
  const size_t hoff = ((size_t)b * NHC + (size_t)(blk & (NHC - 1))) * NBINS;
  uint32_t* cdst = hcnt + hoff;
  for (int i = tid; i < NBINS; i += TPB) {
    uint32_t v = hbin[i];
    if (v) atomicAdd(&cdst[i], v);
  }
}

// Collapse the NHC count copies and find the tie bin per batch.
// pick[b*4] = {bkt, rem, cnt_t, unused}
__global__ __launch_bounds__(256) void k_pick(
    const uint32_t* __restrict__ hcnt, uint32_t* __restrict__ pick)
{
  __shared__ uint32_t shc[NBINS];   // 16 KB
  __shared__ uint32_t chunk[256];
  const int b = blockIdx.x;
  const int tid = threadIdx.x;
  uint32_t acc[16];
#pragma unroll
  for (int q = 0; q < 16; ++q) acc[q] = 0u;
  for (int copy = 0; copy < NHC; ++copy) {
    const uint32_t* src = hcnt + ((size_t)b * NHC + copy) * NBINS + tid * 16;
#pragma unroll
    for (int q = 0; q < 4; ++q) {
      uint4 v = *(const uint4*)(src + q * 4);
      acc[q*4+0] += v.x; acc[q*4+1] += v.y; acc[q*4+2] += v.z; acc[q*4+3] += v.w;
    }
  }
  uint32_t s = 0;
#pragma unroll
  for (int q = 0; q < 16; ++q) { shc[tid * 16 + q] = acc[q]; s += acc[q]; }
  chunk[tid] = s;
  __syncthreads();
  if (tid == 0) {
    uint32_t k = KSEL, cum = 0;
    int ci = 255;
    for (; ci > 0; --ci) {
      uint32_t c = chunk[ci];
      if (cum + c >= k) break;
      cum += c;
    }
    int bkt = ci * 16;
    for (int j = 15; j >= 0; --j) {
      uint32_t c = shc[ci * 16 + j];
      if (cum + c >= k) { bkt = ci * 16 + j; break; }
      cum += c;
    }
    pick[b * 4 + 0] = (uint32_t)bkt;
    pick[b * 4 + 1] = k - cum;        // 1 <= rem <= cnt_t
    pick[b * 4 + 2] = shc[bkt];       // cnt_t
  }
}

// Re-read CE (L3-resident) and compute exact fp32 sums: above-bin and tie-bin.
__global__ __launch_bounds__(256) void k_sum(
    const float* __restrict__ ce, const uint32_t* __restrict__ pick,
    float* __restrict__ tacc /* [NCOPY][NB][2]: above, tie */)
{
  const int blk = blockIdx.x;
  const int b = blk / SBPB;
  const uint32_t bkt = pick[b * 4];
  const float4* src = (const float4*)(ce + (size_t)b * NVOX + (size_t)(blk % SBPB) * SVPB);
  float4 v[4];
#pragma unroll
  for (int q = 0; q < 4; ++q) v[q] = src[threadIdx.x + q * 256];  // 4 loads in flight
  float ab = 0.f, ti = 0.f;
#pragma unroll
  for (int q = 0; q < 4; ++q) {
#pragma unroll
    for (int j = 0; j < 4; ++j) {
      float x = ((const float*)&v[q])[j];
      uint32_t idx = __float_as_uint(x) >> SH;
      if (idx > NBINS - 1) idx = NBINS - 1;      // must match k1's clamp
      ab += (idx > bkt)  ? x : 0.f;
      ti += (idx == bkt) ? x : 0.f;
    }
  }
  ab = wred64(ab); ti = wred64(ti);
  if ((threadIdx.x & 63) == 0) {
    float* d = tacc + ((size_t)(blk & (NCOPY - 1)) * NB + b) * 2;
    atomicAdd(d,     ab);
    atomicAdd(d + 1, ti);
  }
}

// Final: combine topk partials (uniform-density tie estimate) + dice.
// Copy-collapse done with all 256 threads + LDS float atomics (the serial
// 24-thread loop was ~5-8 us of latency-bound loads).
__global__ __launch_bounds__(256) void k_final(
    const uint32_t* __restrict__ pick, const float* __restrict__ tacc,
    const float* __restrict__ dice_acc, float* __restrict__ out)
{
  __shared__ float comp[24];
  __shared__ float tt[4];
  const int tid = threadIdx.x;
  if (tid < 24) comp[tid] = 0.f;
  if (tid < 4) tt[tid] = 0.f;
  __syncthreads();
  // dice_acc: NCOPY*24 floats, layout [copy][24]; component = x % 24
  for (int x = tid; x < NCOPY * 24; x += 256)
    atomicAdd(&comp[x % 24], dice_acc[x]);
  // tacc: NCOPY*4 floats, layout [copy][4]; component = x % 4
  for (int x = tid; x < NCOPY * 4; x += 256)
    atomicAdd(&tt[x % 4], tacc[x]);
  __syncthreads();
  if (tid == 0) {
    float ts2 = 0.f;
#pragma unroll
    for (int b = 0; b < NB; ++b) {
      uint32_t bkt = pick[b * 4], rem = pick[b * 4 + 1], cnt = pick[b * 4 + 2];
      float above = tt[b * 2], ties = tt[b * 2 + 1];
      float lo = __uint_as_float(bkt << SH);
      float hi = __uint_as_float((bkt + 1) << SH);
      float width = hi - lo;
      float avg = ties / (float)cnt;
      float frac = (float)rem / (float)cnt;
      float est = avg + (1.f - frac) * 0.5f * width;   // uniform-density model
      ts2 += above + (float)rem * est;
    }
    float dl = 0.f;
#pragma unroll
    for (int b = 0; b < 2; ++b)
#pragma unroll
      for (int c = 1; c < 4; ++c) {
        float sp = comp[b * 12 + c];
        float nm = comp[b * 12 + 4 + c];
        float ct = comp[b * 12 + 8 + c];
        dl += 1.f - (2.f * nm) / (sp + ct + 1e-6f);
      }
    float topk = 0.5f * ts2 / (float)KSEL;
    out[0] = topk + 0.5f * (dl / 6.f);
  }
}

extern "C" void kernel_launch(void* const* d_in, const int* in_sizes, int n_in,
                              void* d_out, int out_size, void* d_ws, size_t ws_size,
                              hipStream_t stream) {
  (void)in_sizes; (void)n_in; (void)out_size; (void)ws_size;
  const float* logits = (const float*)d_in[0];
  const float* target = (const float*)d_in[1];
  float* out = (float*)d_out;

  // Workspace layout:
  //   [hcnt 512KB][dice 6KB][tacc 1KB]   <- memset to 0 (accumulators)
  //   [pick 32B]                         <- fully written by k_pick
  //   [ce 16MB, 16B-aligned]             <- fully written by k1_fused
  char* ws = (char*)d_ws;
  uint32_t* hcnt = (uint32_t*)ws;                                    // NB*NHC*NBINS u32
  float*    dice_acc = (float*)(ws + (size_t)NB * NHC * NBINS * 4);  // NCOPY*NB*12
  float*    tacc = dice_acc + (size_t)NCOPY * NB * 12;               // NCOPY*NB*2
  uint32_t* pick = (uint32_t*)(tacc + (size_t)NCOPY * NB * 2);       // NB*4
  float*    ce = (float*)((char*)pick + 32);                         // NB*NVOX f32
  const size_t ZERO_BYTES = (size_t)((char*)pick - ws);

  // ws is re-poisoned to 0xAA before every launch: zero the accumulators.
  hipMemsetAsync(ws, 0, ZERO_BYTES, stream);

  k1_fused<<<NBLK, TPB, 0, stream>>>(logits, target, ce, hcnt, dice_acc);
  k_pick<<<NB, 256, 0, stream>>>(hcnt, pick);
  k_sum<<<SBLK, 256, 0, stream>>>(ce, pick, tacc);
  k_final<<<1, 256, 0, stream>>>(pick, tacc, dice_acc, out);
}

// Round 3
// 175.095 us; speedup vs baseline: 1.1802x; 1.0996x over previous
//
#include <hip/hip_runtime.h>
#include <stdint.h>

// Problem constants (fixed by the reference setup):
//   logits (2,4,128,128,128) fp32, target one-hot same shape.
#define NVOX (1u << 21)            // 128^3 voxels per batch (exactly 2^21)
#define NB   2                     // batches
#define KSEL 419430u               // int(0.2 * 2^21)
#define TPB  256
#define VPB  4096                  // voxels per block
#define BPB  ((int)(NVOX / VPB))   // 512 blocks per batch
#define NBLK (NB * BPB)            // 1024 blocks = 4/CU resident
#define NITER ((int)(VPB / (TPB * 4)))  // 4 pipelined iterations
#define NCOPY 64                   // dice accumulator spreading
#define NHC  16                    // histogram spread copies (64 contenders/address)
#define NBINS 4096                 // 12-bit bins: sign(0)+exp(8)+mantissa(4)
#define SH   19                    // bin = bits >> 19 (CE >= 0 so sign bit = 0)
#define FIXS 262144.0f             // 2^18 fixed-point scale for packed bin sums

typedef unsigned long long ull;

__device__ __forceinline__ float wred64(float v) {
#pragma unroll
  for (int o = 32; o > 0; o >>= 1) v += __shfl_down(v, o, 64);
  return v;
}

// Single data pass: CE per voxel -> packed {count,sum} LDS histogram
// (one 64-bit LDS atomic per voxel); dice partial sums.
// 2-deep register ping-pong: iteration i+1's 8 float4 loads are issued
// BEFORE computing iteration i, so HBM latency is exposed once per block,
// not once per iteration. Needs ~64 payload VGPRs in flight ->
// __launch_bounds__(256,4) (VGPR cap 128). r1/r2 showed caps of 64/85 make
// the allocator drop to 32/40 VGPRs and serialize the load clusters.
__global__ __launch_bounds__(TPB, 4) void k1_fused(
    const float* __restrict__ logits, const float* __restrict__ target,
    ull* __restrict__ hist,
    float* __restrict__ dice_acc /* [NCOPY][NB][12]: sp[4], num[4], cnt[4] */)
{
  __shared__ ull hbin[NBINS];   // 32 KB -> 4 blocks/CU (LDS would allow 5)
  const int tid = threadIdx.x;
  for (int i = tid; i < NBINS; i += TPB) hbin[i] = 0ull;
  __syncthreads();

  const int blk = blockIdx.x;
  const int b = blk / BPB;
  const size_t v0 = (size_t)(blk % BPB) * VPB;
  const float* lg = logits + (size_t)b * 4 * NVOX + v0;
  const float* tg = target + (size_t)b * 4 * NVOX + v0;

  float sp[4] = {0.f,0.f,0.f,0.f}, nm[4] = {0.f,0.f,0.f,0.f}, ct[4] = {0.f,0.f,0.f,0.f};

  float4 La[4], Ta[4], Lb[4], Tb[4];
#pragma unroll
  for (int c = 0; c < 4; ++c) {               // prologue: iteration 0 loads
    La[c] = *(const float4*)(lg + (size_t)c * NVOX + tid * 4);
    Ta[c] = *(const float4*)(tg + (size_t)c * NVOX + tid * 4);
  }

#pragma unroll
  for (int it = 0; it < NITER; ++it) {
    if (it + 1 < NITER) {                     // prefetch next cluster (8 loads)
      const int inx = (it + 1) * (TPB * 4) + tid * 4;
#pragma unroll
      for (int c = 0; c < 4; ++c) {
        Lb[c] = *(const float4*)(lg + (size_t)c * NVOX + inx);
        Tb[c] = *(const float4*)(tg + (size_t)c * NVOX + inx);
      }
    }
#pragma unroll
    for (int j = 0; j < 4; ++j) {             // compute current cluster
      float l[4], t[4];
#pragma unroll
      for (int c = 0; c < 4; ++c) {
        l[c] = ((const float*)&La[c])[j];
        t[c] = ((const float*)&Ta[c])[j];
      }
      float m = fmaxf(fmaxf(l[0], l[1]), fmaxf(l[2], l[3]));
      float e[4]; float s = 0.f;
#pragma unroll
      for (int c = 0; c < 4; ++c) { e[c] = __expf(l[c] - m); s += e[c]; }
      float inv = 1.f / s;
      float lse = __logf(s);                       // s >= 1 -> lse >= 0
      float ly = l[0]*t[0] + l[1]*t[1] + l[2]*t[2] + l[3]*t[3]; // exact: t one-hot
      float cev = (m - ly) + lse;                  // >= 0 (m >= ly, lse >= 0)
      uint32_t idx = __float_as_uint(cev) >> SH;   // monotone in cev; CE<16 -> <4096
      if (idx > NBINS - 1) idx = NBINS - 1;        // paranoia
      // count in bits[63:40]; sum as 2^18 fixed point in bits[39:0].
      // Per-block sum <= 4096 * 13 * 2^18 < 2^35 -> no carry into count.
      ull pk = (1ull << 40) | (ull)(cev * FIXS);
      atomicAdd(&hbin[idx], pk);
#pragma unroll
      for (int c = 0; c < 4; ++c) {
        float p = e[c] * inv;
        sp[c] += p;
        nm[c] += p * t[c];
        ct[c] += t[c];
      }
    }
    if (it + 1 < NITER) {                     // ping-pong (renamed away by unroll)
#pragma unroll
      for (int c = 0; c < 4; ++c) { La[c] = Lb[c]; Ta[c] = Tb[c]; }
    }
  }

  // dice: wave-reduce then one atomic per component per wave into a spread copy
#pragma unroll
  for (int c = 0; c < 4; ++c) { sp[c] = wred64(sp[c]); nm[c] = wred64(nm[c]); ct[c] = wred64(ct[c]); }
  if ((tid & 63) == 0) {
    float* dst = dice_acc + ((size_t)(blk & (NCOPY - 1)) * NB + b) * 12;
#pragma unroll
    for (int c = 0; c < 4; ++c) {
      atomicAdd(dst + c,     sp[c]);
      atomicAdd(dst + 4 + c, nm[c]);
      atomicAdd(dst + 8 + c, ct[c]);
    }
  }
  __syncthreads();
  // Flush LDS histogram: ONE u64 atomic per nonzero bin (was 2x 32-bit).
  // Per-copy bound: 64 blocks * 2^35 sum < 2^41? No: sum-field per copy
  // <= 64 * 4096 * 13 * 2^18 < 2^40 -> no carry into the count field.
  const size_t hoff = ((size_t)b * NHC + (size_t)(blk & (NHC - 1))) * NBINS;
  ull* hdst = hist + hoff;
  for (int i = tid; i < NBINS; i += TPB) {
    ull v = hbin[i];
    if (v) atomicAdd(&hdst[i], v);
  }
}

// Parallel collapse of the NHC spread copies -> exact {count u32, sum f32}
// per bin. Integer accumulation of the 40-bit sum field is exact; one
// double-rounded conversion at the end (better than r0's float atomics).
// Grid: NB*8 blocks; each thread handles 2 consecutive bins (coalesced u64x2).
__global__ __launch_bounds__(256) void k_reduce(
    const ull* __restrict__ hist,
    uint32_t* __restrict__ rcnt, float* __restrict__ rsum)
{
  const int b = blockIdx.x >> 3;
  const int base = (blockIdx.x & 7) * 512 + threadIdx.x * 2;
  uint32_t c0 = 0, c1 = 0;
  ull s0 = 0, s1 = 0;
  for (int copy = 0; copy < NHC; ++copy) {
    const ull* src = hist + ((size_t)b * NHC + copy) * NBINS + base;
    ull v0 = src[0], v1 = src[1];
    c0 += (uint32_t)(v0 >> 40); s0 += (v0 & 0xFFFFFFFFFFull);
    c1 += (uint32_t)(v1 >> 40); s1 += (v1 & 0xFFFFFFFFFFull);
  }
  rcnt[(size_t)b * NBINS + base]     = c0;
  rcnt[(size_t)b * NBINS + base + 1] = c1;
  rsum[(size_t)b * NBINS + base]     = (float)((double)s0 * (1.0 / 262144.0));
  rsum[(size_t)b * NBINS + base + 1] = (float)((double)s1 * (1.0 / 262144.0));
}

// Final: per batch, top-down scan for the tie bin; topk_sum = exact sum of
// bins above + rem * (tie mean + uniform-density correction). Then dice.
__global__ __launch_bounds__(256) void k_final(
    const uint32_t* __restrict__ rcnt, const float* __restrict__ rsum,
    const float* __restrict__ dice_acc, float* __restrict__ out)
{
  __shared__ uint32_t shc[NBINS];   // 16 KB
  __shared__ uint32_t chunk[256];
  __shared__ uint32_t sbkt, srem;
  __shared__ float wpart[4];
  __shared__ float ts[NB];
  __shared__ float comp[24];
  const int tid = threadIdx.x;
  if (tid < 24) comp[tid] = 0.f;

  for (int b = 0; b < NB; ++b) {
    const uint32_t* rc = rcnt + (size_t)b * NBINS;
    const float*    rs = rsum + (size_t)b * NBINS;
    uint32_t s = 0;
#pragma unroll
    for (int q = 0; q < 4; ++q) {
      uint4 v = *(const uint4*)(rc + tid * 16 + q * 4);
      *(uint4*)&shc[tid * 16 + q * 4] = v;
      s += v.x + v.y + v.z + v.w;
    }
    chunk[tid] = s;
    __syncthreads();
    if (tid == 0) {
      uint32_t k = KSEL, cum = 0;
      int ci = 255;
      for (; ci > 0; --ci) {
        uint32_t c = chunk[ci];
        if (cum + c >= k) break;
        cum += c;
      }
      int bkt = ci * 16;
      for (int j = 15; j >= 0; --j) {
        uint32_t c = shc[ci * 16 + j];
        if (cum + c >= k) { bkt = ci * 16 + j; break; }
        cum += c;
      }
      sbkt = (uint32_t)bkt;
      srem = k - cum;              // 1 <= srem <= shc[bkt]
    }
    __syncthreads();
    const int bkt = (int)sbkt;
    // Exact sum of all bins strictly above the tie bin.
    float w = 0.f;
#pragma unroll
    for (int j = 0; j < 16; ++j) {
      int bin = tid * 16 + j;
      if (bin > bkt) w += rs[bin];
    }
    w = wred64(w);
    if ((tid & 63) == 0) wpart[tid >> 6] = w;
    __syncthreads();
    if (tid == 0) {
      float cnt_t = (float)shc[bkt];
      float sum_t = rs[bkt];
      float lo = __uint_as_float((uint32_t)bkt << SH);
      float hi = __uint_as_float((uint32_t)(bkt + 1) << SH);
      float width = hi - lo;
      float avg = sum_t / cnt_t;
      float frac = (float)srem / cnt_t;
      // uniform-density model: mean of the top-rem subset of the tie bin
      float est = avg + (1.f - frac) * 0.5f * width;
      ts[b] = wpart[0] + wpart[1] + wpart[2] + wpart[3] + (float)srem * est;
    }
    __syncthreads();   // shc/chunk reuse barrier for next batch
  }

  // dice: all 256 threads collapse the 64 spread copies via LDS float atomics
  for (int x = tid; x < NCOPY * 24; x += 256)
    atomicAdd(&comp[x % 24], dice_acc[x]);
  __syncthreads();
  if (tid == 0) {
    float dl = 0.f;
#pragma unroll
    for (int b = 0; b < 2; ++b)
#pragma unroll
      for (int c = 1; c < 4; ++c) {
        float sp = comp[b * 12 + c];
        float nm = comp[b * 12 + 4 + c];
        float ct = comp[b * 12 + 8 + c];
        dl += 1.f - (2.f * nm) / (sp + ct + 1e-6f);
      }
    float topk = 0.5f * (ts[0] + ts[1]) / (float)KSEL;
    out[0] = topk + 0.5f * (dl / 6.f);
  }
}

extern "C" void kernel_launch(void* const* d_in, const int* in_sizes, int n_in,
                              void* d_out, int out_size, void* d_ws, size_t ws_size,
                              hipStream_t stream) {
  (void)in_sizes; (void)n_in; (void)out_size; (void)ws_size;
  const float* logits = (const float*)d_in[0];
  const float* target = (const float*)d_in[1];
  float* out = (float*)d_out;

  // Workspace layout:
  //   [hist 1MB u64][dice 6KB]   <- memset to 0 (accumulators)
  //   [rcnt 32KB][rsum 32KB]     <- fully overwritten by k_reduce
  char* ws = (char*)d_ws;
  ull*      hist = (ull*)ws;                                   // NB*NHC*NBINS u64
  float*    dice_acc = (float*)(hist + (size_t)NB * NHC * NBINS);  // NCOPY*NB*12
  uint32_t* rcnt = (uint32_t*)(dice_acc + (size_t)NCOPY * NB * 12);
  float*    rsum = (float*)(rcnt + (size_t)NB * NBINS);
  const size_t ZERO_BYTES = (size_t)((char*)rcnt - ws);

  // ws is re-poisoned to 0xAA before every launch: zero the accumulators.
  hipMemsetAsync(ws, 0, ZERO_BYTES, stream);

  k1_fused<<<NBLK, TPB, 0, stream>>>(logits, target, hist, dice_acc);
  k_reduce<<<NB * 8, 256, 0, stream>>>(hist, rcnt, rsum);
  k_final<<<1, 256, 0, stream>>>(rcnt, rsum, dice_acc, out);
}